// Round 3
// baseline (12146.955 us; speedup 1.0000x reference)
//
#include <hip/hip_runtime.h>

#define DEV __device__ __forceinline__

namespace {
constexpr int Bc = 32;
constexpr int Tc = 256;
constexpr int Dc = 512;
constexpr int Sc = 2048;
constexpr int NBLK = 256;
constexpr int NW   = 128;          // writer blocks
constexpr int ROWS = Sc / NW;      // 16 memory rows per W block

// workspace layout (float offsets)
constexpr size_t OFF_KN  = 0;                                   // [T][B][D] normalized k
constexpr size_t OFF_E   = OFF_KN  + (size_t)Tc * Bc * Dc;      // [T][B][D] sigmoid(erase)
constexpr size_t OFF_A   = OFF_E   + (size_t)Tc * Bc * Dc;      // [T][B][D] add
constexpr size_t OFF_MEM = OFF_A   + (size_t)Tc * Bc * Dc;      // [2][S][D] memory ping-pong
constexpr size_t OFF_EW  = OFF_MEM + (size_t)2 * Sc * Dc;       // [2][S][B] exp(sim)
constexpr size_t OFF_RP  = OFF_EW  + (size_t)2 * Sc * Bc;       // [2][16][B][D] read partials
constexpr size_t OFF_DEN = OFF_RP  + (size_t)2 * 16 * Bc * Dc;  // [T][B] softmax denominators
constexpr size_t OFF_CNT = OFF_DEN + (size_t)Tc * Bc;           // barrier counter (u32)
}

DEV float sigm(float x) { return 1.0f / (1.0f + __expf(-x)); }

// ---------------------------------------------------------------------------
// Coherent (agent-scope, sc1) load/store helpers: plain pipelined global ops
// performed at the device coherent point (no L2 flush/inv instructions).
// ---------------------------------------------------------------------------
DEV float ld1cg(const float* p) {
  unsigned u = __hip_atomic_load((const unsigned*)p, __ATOMIC_RELAXED,
                                 __HIP_MEMORY_SCOPE_AGENT);
  return __uint_as_float(u);
}
DEV void st1cg(float* p, float v) {
  __hip_atomic_store((unsigned*)p, __float_as_uint(v), __ATOMIC_RELAXED,
                     __HIP_MEMORY_SCOPE_AGENT);
}
DEV float2 ld2cg(const float* p) {
  unsigned long long u = __hip_atomic_load((const unsigned long long*)p,
                                           __ATOMIC_RELAXED, __HIP_MEMORY_SCOPE_AGENT);
  union { unsigned long long u; float2 f; } c; c.u = u; return c.f;
}
DEV void st2cg(float* p, float2 v) {
  union { float2 f; unsigned long long u; } c; c.f = v;
  __hip_atomic_store((unsigned long long*)p, c.u, __ATOMIC_RELAXED,
                     __HIP_MEMORY_SCOPE_AGENT);
}

// ---------------------------------------------------------------------------
// K1: C[r][j] = sum_d A[r][d] * W[j][d] + bias[j], for 4 weight matrices.
// ---------------------------------------------------------------------------
__global__ __launch_bounds__(256) void k_gemm(
    const float* __restrict__ A,
    const float* __restrict__ Wk, const float* __restrict__ bk,
    const float* __restrict__ We, const float* __restrict__ be,
    const float* __restrict__ Ww, const float* __restrict__ bw,
    const float* __restrict__ Wg, const float* __restrict__ bg,
    float* __restrict__ ws, float* __restrict__ gout)
{
  __shared__ float As[32][68];
  __shared__ float Bs[32][68];

  const int bid = blockIdx.x;
  const int mat = bid >> 10;
  const int rem = bid & 1023;
  const int rt = rem >> 3, jt = rem & 7;
  const int rbase = rt * 64, jbase = jt * 64;

  const float* Wm; const float* bm;
  if      (mat == 0) { Wm = Wk; bm = bk; }
  else if (mat == 1) { Wm = We; bm = be; }
  else if (mat == 2) { Wm = Ww; bm = bw; }
  else               { Wm = Wg; bm = bg; }

  const int tid = threadIdx.x;
  const int lr = tid >> 2;
  const int lk = (tid & 3) * 8;
  const int ty = tid >> 4, tx = tid & 15;

  float acc[4][4] = {};

  for (int k0 = 0; k0 < Dc; k0 += 32) {
    const float4 a0 = *(const float4*)&A [(size_t)(rbase + lr) * Dc + k0 + lk];
    const float4 a1 = *(const float4*)&A [(size_t)(rbase + lr) * Dc + k0 + lk + 4];
    const float4 b0 = *(const float4*)&Wm[(size_t)(jbase + lr) * Dc + k0 + lk];
    const float4 b1 = *(const float4*)&Wm[(size_t)(jbase + lr) * Dc + k0 + lk + 4];
    __syncthreads();
    As[lk + 0][lr] = a0.x; As[lk + 1][lr] = a0.y; As[lk + 2][lr] = a0.z; As[lk + 3][lr] = a0.w;
    As[lk + 4][lr] = a1.x; As[lk + 5][lr] = a1.y; As[lk + 6][lr] = a1.z; As[lk + 7][lr] = a1.w;
    Bs[lk + 0][lr] = b0.x; Bs[lk + 1][lr] = b0.y; Bs[lk + 2][lr] = b0.z; Bs[lk + 3][lr] = b0.w;
    Bs[lk + 4][lr] = b1.x; Bs[lk + 5][lr] = b1.y; Bs[lk + 6][lr] = b1.z; Bs[lk + 7][lr] = b1.w;
    __syncthreads();
    #pragma unroll
    for (int kk = 0; kk < 32; ++kk) {
      const float4 av = *(const float4*)&As[kk][ty * 4];
      const float4 bv = *(const float4*)&Bs[kk][tx * 4];
      const float ar[4] = {av.x, av.y, av.z, av.w};
      const float br[4] = {bv.x, bv.y, bv.z, bv.w};
      #pragma unroll
      for (int i = 0; i < 4; ++i)
        #pragma unroll
        for (int j = 0; j < 4; ++j)
          acc[i][j] = fmaf(ar[i], br[j], acc[i][j]);
    }
  }

  const float4 bias = *(const float4*)&bm[jbase + tx * 4];
  const float bi[4] = {bias.x, bias.y, bias.z, bias.w};
  #pragma unroll
  for (int i = 0; i < 4; ++i) {
    const int r = rbase + ty * 4 + i;
    float v[4];
    #pragma unroll
    for (int j = 0; j < 4; ++j) {
      v[j] = acc[i][j] + bi[j];
      if (mat & 1) v[j] = sigm(v[j]);
    }
    float4 o; o.x = v[0]; o.y = v[1]; o.z = v[2]; o.w = v[3];
    if (mat == 3) {
      *(float4*)&gout[(size_t)r * Dc + jbase + tx * 4] = o;   // g -> d_out (temp)
    } else {
      float* dst = ws + (mat == 0 ? OFF_KN : (mat == 1 ? OFF_E : OFF_A));
      const int t = r & 255, b = r >> 8;                      // r = b*T + t
      *(float4*)&dst[((size_t)t * Bc + b) * Dc + jbase + tx * 4] = o;
    }
  }
}

// ---------------------------------------------------------------------------
// K2: l2-normalize each of the T*B rows of k in place.
// ---------------------------------------------------------------------------
__global__ __launch_bounds__(256) void k_knorm(float* __restrict__ kn)
{
  const int row = blockIdx.x * 4 + (threadIdx.x >> 6);
  const int lane = threadIdx.x & 63;
  float* p = kn + (size_t)row * Dc;
  float4 v0 = *(const float4*)&p[lane * 4];
  float4 v1 = *(const float4*)&p[256 + lane * 4];
  float ss = v0.x*v0.x + v0.y*v0.y + v0.z*v0.z + v0.w*v0.w
           + v1.x*v1.x + v1.y*v1.y + v1.z*v1.z + v1.w*v1.w;
  #pragma unroll
  for (int off = 32; off >= 1; off >>= 1) ss += __shfl_xor(ss, off);
  const float inv = 1.0f / fmaxf(sqrtf(ss), 1e-12f);
  v0.x *= inv; v0.y *= inv; v0.z *= inv; v0.w *= inv;
  v1.x *= inv; v1.y *= inv; v1.z *= inv; v1.w *= inv;
  *(float4*)&p[lane * 4] = v0;
  *(float4*)&p[256 + lane * 4] = v1;
}

// ---------------------------------------------------------------------------
// sim phase: xbuf holds 16 freshly written memory rows. Writes ew rows (sc1)
// and atomicAdds the softmax denominators (device-scope).
// ---------------------------------------------------------------------------
DEV void sim_phase(const float* __restrict__ knp, float* __restrict__ ewn,
                   float* __restrict__ denp, float (*xb)[516],
                   const float* invn_s, float* sred, int s0, int tid)
{
  const int r = tid >> 4, bp = tid & 15;
  const float* k0p = knp + (size_t)bp * Dc;
  const float* k1p = knp + (size_t)(bp + 16) * Dc;
  float acc0 = 0.f, acc1 = 0.f;
  #pragma unroll 4
  for (int dq = 0; dq < Dc / 4; ++dq) {
    const float4 y4 = *(const float4*)&xb[r][dq * 4];
    const float4 ka = *(const float4*)&k0p[dq * 4];
    const float4 kb = *(const float4*)&k1p[dq * 4];
    acc0 = fmaf(y4.x, ka.x, acc0); acc0 = fmaf(y4.y, ka.y, acc0);
    acc0 = fmaf(y4.z, ka.z, acc0); acc0 = fmaf(y4.w, ka.w, acc0);
    acc1 = fmaf(y4.x, kb.x, acc1); acc1 = fmaf(y4.y, kb.y, acc1);
    acc1 = fmaf(y4.z, kb.z, acc1); acc1 = fmaf(y4.w, kb.w, acc1);
  }
  const float iv = invn_s[r];
  const float e0 = __expf(acc0 * iv);
  const float e1 = __expf(acc1 * iv);
  st1cg(&ewn[(size_t)(s0 + r) * Bc + bp], e0);
  st1cg(&ewn[(size_t)(s0 + r) * Bc + bp + 16], e1);
  if (tid < 32) sred[tid] = 0.f;
  __syncthreads();
  atomicAdd(&sred[bp], e0);
  atomicAdd(&sred[bp + 16], e1);
  __syncthreads();
  if (tid < 32) atomicAdd(&denp[tid], sred[tid]);
}

// ---------------------------------------------------------------------------
// Prologue: copy mem -> buf0, compute ew_0 / den_0. Grid = 128 blocks.
// ---------------------------------------------------------------------------
__global__ __launch_bounds__(256) void k_prologue(
    const float* __restrict__ mem_in, float* __restrict__ ws)
{
  __shared__ float xbuf[16][516];
  __shared__ float sred[32];
  __shared__ float invn_s[16];

  float* kn   = ws + OFF_KN;
  float* memb = ws + OFF_MEM;
  float* ewb  = ws + OFF_EW;
  float* den  = ws + OFF_DEN;

  const int bid = blockIdx.x, tid = threadIdx.x;
  const int s0 = bid * ROWS;
  const int c0 = tid * 2;
  #pragma unroll
  for (int r = 0; r < ROWS; ++r) {
    const float2 m = *(const float2*)&mem_in[(size_t)(s0 + r) * Dc + c0];
    *(float2*)&xbuf[r][c0] = m;
    st2cg(&memb[(size_t)(s0 + r) * Dc + c0], m);
  }
  __syncthreads();
  {
    const int row = tid >> 4, li = tid & 15;
    float ss = 0.f;
    #pragma unroll
    for (int i = 0; i < 8; ++i) {
      const float4 v = *(const float4*)&xbuf[row][(li + i * 16) * 4];
      ss += v.x*v.x + v.y*v.y + v.z*v.z + v.w*v.w;
    }
    ss += __shfl_xor(ss, 8); ss += __shfl_xor(ss, 4);
    ss += __shfl_xor(ss, 2); ss += __shfl_xor(ss, 1);
    if (li == 0) invn_s[row] = 1.0f / fmaxf(sqrtf(ss), 1e-12f);
  }
  __syncthreads();
  sim_phase(kn, ewb, den, xbuf, invn_s, sred, s0, tid);
}

// ---------------------------------------------------------------------------
// Persistent step kernel: 256 blocks, one lightweight device barrier per step.
// No cache-maintenance ops: all cross-step state moves via sc1 (agent-scope
// relaxed atomic) loads/stores at the coherent point.
// ---------------------------------------------------------------------------
DEV void gbar(unsigned* cnt, unsigned target)
{
  __syncthreads();   // compiler drains vmcnt before s_barrier -> release
  if (threadIdx.x == 0) {
    __hip_atomic_fetch_add(cnt, 1u, __ATOMIC_RELAXED, __HIP_MEMORY_SCOPE_AGENT);
    unsigned v = __hip_atomic_load(cnt, __ATOMIC_RELAXED, __HIP_MEMORY_SCOPE_AGENT);
    while (v < target) {
      __builtin_amdgcn_s_sleep(2);
      v = __hip_atomic_load(cnt, __ATOMIC_RELAXED, __HIP_MEMORY_SCOPE_AGENT);
    }
  }
  __syncthreads();
}

__global__ __launch_bounds__(256) void k_main(
    const float* __restrict__ cs,
    const float* __restrict__ gamma, const float* __restrict__ beta,
    float* __restrict__ ws, float* __restrict__ out)
{
  __shared__ float xbuf[16][516];
  __shared__ float wbuf[16][32];
  __shared__ float sred[32];
  __shared__ float mu_s[16], rs_s[16], invn_s[16];
  __shared__ float dinv_s[32];

  float* kn   = ws + OFF_KN;
  float* eptb = ws + OFF_E;
  float* aptb = ws + OFF_A;
  float* memb = ws + OFF_MEM;
  float* ewb  = ws + OFF_EW;
  float* rp   = ws + OFF_RP;
  float* den  = ws + OFF_DEN;
  unsigned* cnt = (unsigned*)(ws + OFF_CNT);

  const int bid = blockIdx.x, tid = threadIdx.x;
  const float inv32 = 1.0f / 32.0f;
  unsigned bart = 0;

  for (int t = 0; t <= Tc; ++t) {
    if (bid < NW) {
      if (t < Tc - 1) {
        const int s0 = bid * ROWS;
        const int c0 = tid * 2;
        const float* ewc = ewb + (size_t)(t & 1) * Sc * Bc;
        float*       ewn = ewb + (size_t)((t + 1) & 1) * Sc * Bc;
        const float* memc = memb + (size_t)(t & 1) * Sc * Dc;
        float*       memn = memb + (size_t)((t + 1) & 1) * Sc * Dc;

        if (tid < 32) dinv_s[tid] = 1.0f / ld1cg(&den[(size_t)t * Bc + tid]);
        __syncthreads();
        for (int idx = tid; idx < ROWS * 32; idx += 256) {
          const int r = idx >> 5, b = idx & 31;
          wbuf[r][b] = ld1cg(&ewc[(size_t)(s0 + r) * Bc + b]) * dinv_s[b];
        }
        __syncthreads();

        // rank-32 erase/add update
        float2 er[ROWS] = {}, ad[ROWS] = {};
        const float* ept = eptb + (size_t)t * Bc * Dc;
        const float* apt = aptb + (size_t)t * Bc * Dc;
        #pragma unroll 4
        for (int b = 0; b < 32; ++b) {
          const float2 ev = *(const float2*)&ept[(size_t)b * Dc + c0];
          const float2 av = *(const float2*)&apt[(size_t)b * Dc + c0];
          #pragma unroll
          for (int r = 0; r < ROWS; ++r) {
            const float wv = wbuf[r][b];
            er[r].x = fmaf(wv, ev.x, er[r].x); er[r].y = fmaf(wv, ev.y, er[r].y);
            ad[r].x = fmaf(wv, av.x, ad[r].x); ad[r].y = fmaf(wv, av.y, ad[r].y);
          }
        }
        float2 xr[ROWS];
        #pragma unroll
        for (int r = 0; r < ROWS; ++r) {
          const float2 m = ld2cg(&memc[(size_t)(s0 + r) * Dc + c0]);
          float2 x;
          x.x = m.x * (1.0f - er[r].x * inv32) + ad[r].x * inv32;
          x.y = m.y * (1.0f - er[r].y * inv32) + ad[r].y * inv32;
          xr[r] = x;
          *(float2*)&xbuf[r][c0] = x;
        }
        __syncthreads();
        // LN stats per row
        {
          const int row = tid >> 4, li = tid & 15;
          float s1 = 0.f, s2 = 0.f;
          #pragma unroll
          for (int i = 0; i < 8; ++i) {
            const float4 v = *(const float4*)&xbuf[row][(li + i * 16) * 4];
            s1 += v.x + v.y + v.z + v.w;
            s2 += v.x*v.x + v.y*v.y + v.z*v.z + v.w*v.w;
          }
          s1 += __shfl_xor(s1, 8); s2 += __shfl_xor(s2, 8);
          s1 += __shfl_xor(s1, 4); s2 += __shfl_xor(s2, 4);
          s1 += __shfl_xor(s1, 2); s2 += __shfl_xor(s2, 2);
          s1 += __shfl_xor(s1, 1); s2 += __shfl_xor(s2, 1);
          if (li == 0) {
            const float mu = s1 * (1.0f / 512.0f);
            const float var = s2 * (1.0f / 512.0f) - mu * mu;
            mu_s[row] = mu;
            rs_s[row] = rsqrtf(var + 1e-5f);
          }
        }
        __syncthreads();
        const float2 gm  = *(const float2*)&gamma[c0];
        const float2 bt2 = *(const float2*)&beta[c0];
        #pragma unroll
        for (int r = 0; r < ROWS; ++r) {
          const float mu = mu_s[r], rs = rs_s[r];
          float2 y;
          y.x = (xr[r].x - mu) * rs * gm.x + bt2.x;
          y.y = (xr[r].y - mu) * rs * gm.y + bt2.y;
          *(float2*)&xbuf[r][c0] = y;
          st2cg(&memn[(size_t)(s0 + r) * Dc + c0], y);
        }
        __syncthreads();
        // row l2 norms of new memory
        {
          const int row = tid >> 4, li = tid & 15;
          float ss = 0.f;
          #pragma unroll
          for (int i = 0; i < 8; ++i) {
            const float4 v = *(const float4*)&xbuf[row][(li + i * 16) * 4];
            ss += v.x*v.x + v.y*v.y + v.z*v.z + v.w*v.w;
          }
          ss += __shfl_xor(ss, 8); ss += __shfl_xor(ss, 4);
          ss += __shfl_xor(ss, 2); ss += __shfl_xor(ss, 1);
          if (li == 0) invn_s[row] = 1.0f / fmaxf(sqrtf(ss), 1e-12f);
        }
        __syncthreads();
        sim_phase(kn + (size_t)(t + 1) * Bc * Dc, ewn,
                  den + (size_t)(t + 1) * Bc, xbuf, invn_s, sred, s0, tid);
      }
    } else {
      const int rb = bid - NW;
      // O duty: gated output for step t-1
      if (rb < 8 && t >= 1) {
        const int t0 = t - 1;
        const float* rpc = rp + (size_t)(t0 & 1) * 16 * Bc * Dc;
        const int base = (rb * 256 + tid) * 8;
        const int b = base >> 9, d0 = base & 511;
        const float inv = 1.0f / ld1cg(&den[(size_t)t0 * Bc + b]);
        float r0[8] = {};
        #pragma unroll
        for (int si = 0; si < 16; ++si) {
          const float* q = rpc + ((size_t)si * Bc + b) * Dc + d0;
          const float2 p0 = ld2cg(q + 0);
          const float2 p1 = ld2cg(q + 2);
          const float2 p2 = ld2cg(q + 4);
          const float2 p3 = ld2cg(q + 6);
          r0[0] += p0.x; r0[1] += p0.y; r0[2] += p1.x; r0[3] += p1.y;
          r0[4] += p2.x; r0[5] += p2.y; r0[6] += p3.x; r0[7] += p3.y;
        }
        const size_t oofs = ((size_t)b * Tc + t0) * Dc + d0;
        const float4 g0 = *(const float4*)&out[oofs];
        const float4 g1 = *(const float4*)&out[oofs + 4];
        const float4 c0v = *(const float4*)&cs[oofs];
        const float4 c1v = *(const float4*)&cs[oofs + 4];
        float4 o0, o1;
        o0.x = g0.x * c0v.x + (1.0f - g0.x) * (r0[0] * inv);
        o0.y = g0.y * c0v.y + (1.0f - g0.y) * (r0[1] * inv);
        o0.z = g0.z * c0v.z + (1.0f - g0.z) * (r0[2] * inv);
        o0.w = g0.w * c0v.w + (1.0f - g0.w) * (r0[3] * inv);
        o1.x = g1.x * c1v.x + (1.0f - g1.x) * (r0[4] * inv);
        o1.y = g1.y * c1v.y + (1.0f - g1.y) * (r0[5] * inv);
        o1.z = g1.z * c1v.z + (1.0f - g1.z) * (r0[6] * inv);
        o1.w = g1.w * c1v.w + (1.0f - g1.w) * (r0[7] * inv);
        *(float4*)&out[oofs] = o0;
        *(float4*)&out[oofs + 4] = o1;
      }
      // R duty: unnormalized read partials for step t
      if (t < Tc) {
        const int si = rb >> 3, dj = rb & 7;
        const int sB = si * 128;
        const float* ewc = ewb + (size_t)(t & 1) * Sc * Bc;
        const float* memc = memb + (size_t)(t & 1) * Sc * Dc;
        float* ewl = (float*)xbuf;
        for (int i = tid; i < 128 * 32; i += 256)
          ewl[i] = ld1cg(&ewc[(size_t)sB * Bc + i]);
        __syncthreads();
        const int b = tid >> 3, dg = tid & 7;
        const int cbase = dj * 64 + dg * 8;
        float a0[8] = {};
        #pragma unroll 2
        for (int s = 0; s < 128; ++s) {
          const float wv = ewl[s * 32 + b];
          const float* mrow = memc + (size_t)(sB + s) * Dc + cbase;
          const float2 m0 = ld2cg(mrow + 0);
          const float2 m1 = ld2cg(mrow + 2);
          const float2 m2 = ld2cg(mrow + 4);
          const float2 m3 = ld2cg(mrow + 6);
          a0[0] = fmaf(wv, m0.x, a0[0]); a0[1] = fmaf(wv, m0.y, a0[1]);
          a0[2] = fmaf(wv, m1.x, a0[2]); a0[3] = fmaf(wv, m1.y, a0[3]);
          a0[4] = fmaf(wv, m2.x, a0[4]); a0[5] = fmaf(wv, m2.y, a0[5]);
          a0[6] = fmaf(wv, m3.x, a0[6]); a0[7] = fmaf(wv, m3.y, a0[7]);
        }
        float* dst = rp + (size_t)(t & 1) * 16 * Bc * Dc + ((size_t)si * Bc + b) * Dc + cbase;
        float2 w0; w0.x = a0[0]; w0.y = a0[1]; st2cg(dst + 0, w0);
        float2 w1; w1.x = a0[2]; w1.y = a0[3]; st2cg(dst + 2, w1);
        float2 w2; w2.x = a0[4]; w2.y = a0[5]; st2cg(dst + 4, w2);
        float2 w3; w3.x = a0[6]; w3.y = a0[7]; st2cg(dst + 6, w3);
        __syncthreads();
      }
    }
    if (t < Tc) { bart += NBLK; gbar(cnt, bart); }
  }
}

// ---------------------------------------------------------------------------
extern "C" void kernel_launch(void* const* d_in, const int* in_sizes, int n_in,
                              void* d_out, int out_size, void* d_ws, size_t ws_size,
                              hipStream_t stream)
{
  const float* cs    = (const float*)d_in[0];
  const float* mem   = (const float*)d_in[1];
  const float* Wk    = (const float*)d_in[2];
  const float* bk    = (const float*)d_in[3];
  const float* We    = (const float*)d_in[4];
  const float* be    = (const float*)d_in[5];
  const float* Ww    = (const float*)d_in[6];
  const float* bw    = (const float*)d_in[7];
  const float* Wg    = (const float*)d_in[8];
  const float* bg    = (const float*)d_in[9];
  const float* gamma = (const float*)d_in[10];
  const float* beta  = (const float*)d_in[11];
  float* ws  = (float*)d_ws;
  float* out = (float*)d_out;

  // zero softmax denominators + barrier counter (contiguous)
  hipMemsetAsync(ws + OFF_DEN, 0, ((size_t)Tc * Bc + 1) * sizeof(float), stream);

  hipLaunchKernelGGL(k_gemm, dim3(4096), dim3(256), 0, stream,
                     cs, Wk, bk, We, be, Ww, bw, Wg, bg, ws, out);
  hipLaunchKernelGGL(k_knorm, dim3(2048), dim3(256), 0, stream, ws + OFF_KN);
  hipLaunchKernelGGL(k_prologue, dim3(NW), dim3(256), 0, stream, mem, ws);
  hipLaunchKernelGGL(k_main, dim3(NBLK), dim3(256), 0, stream,
                     cs, gamma, beta, ws, out);
}

// Round 4
// 12118.029 us; speedup vs baseline: 1.0024x; 1.0024x over previous
//
#include <hip/hip_runtime.h>

#define DEV __device__ __forceinline__

namespace {
constexpr int Bc = 32;
constexpr int Tc = 256;
constexpr int Dc = 512;
constexpr int Sc = 2048;
constexpr int NBLK = 256;
constexpr int NW   = 128;          // writer blocks
constexpr int ROWS = Sc / NW;      // 16 memory rows per W block

// workspace layout (float offsets)
constexpr size_t OFF_KN   = 0;                                   // [T][B][D] normalized k
constexpr size_t OFF_E    = OFF_KN  + (size_t)Tc * Bc * Dc;      // [T][B][D] sigmoid(erase)
constexpr size_t OFF_A    = OFF_E   + (size_t)Tc * Bc * Dc;      // [T][B][D] add
constexpr size_t OFF_MEM  = OFF_A   + (size_t)Tc * Bc * Dc;      // [2][S][D] memory ping-pong
constexpr size_t OFF_EW   = OFF_MEM + (size_t)2 * Sc * Dc;       // [2][S][B] exp(sim)
constexpr size_t OFF_RP   = OFF_EW  + (size_t)2 * Sc * Bc;       // [2][16][B][D] read partials
constexpr size_t OFF_DEN  = OFF_RP  + (size_t)2 * 16 * Bc * Dc;  // [T][B] softmax denominators
constexpr size_t OFF_DENP = OFF_DEN + (size_t)Tc * Bc;           // [2][NW][B] den partials
constexpr size_t OFF_FLAGS= OFF_DENP+ (size_t)2 * NW * Bc;       // 256*16 u32 arrival flags
constexpr size_t OFF_GO   = OFF_FLAGS + 256 * 16;                // 1 u32 release word
}

DEV float sigm(float x) { return 1.0f / (1.0f + __expf(-x)); }

// Agent-scope relaxed (sc1) helpers: pipelined global ops at the device
// coherent point; no cache-maintenance instructions.
DEV float ld1cg(const float* p) {
  unsigned u = __hip_atomic_load((const unsigned*)p, __ATOMIC_RELAXED,
                                 __HIP_MEMORY_SCOPE_AGENT);
  return __uint_as_float(u);
}
DEV void st1cg(float* p, float v) {
  __hip_atomic_store((unsigned*)p, __float_as_uint(v), __ATOMIC_RELAXED,
                     __HIP_MEMORY_SCOPE_AGENT);
}
DEV float2 ld2cg(const float* p) {
  unsigned long long u = __hip_atomic_load((const unsigned long long*)p,
                                           __ATOMIC_RELAXED, __HIP_MEMORY_SCOPE_AGENT);
  union { unsigned long long u; float2 f; } c; c.u = u; return c.f;
}
DEV void st2cg(float* p, float2 v) {
  union { float2 f; unsigned long long u; } c; c.f = v;
  __hip_atomic_store((unsigned long long*)p, c.u, __ATOMIC_RELAXED,
                     __HIP_MEMORY_SCOPE_AGENT);
}

// ---------------------------------------------------------------------------
// K1: 4 fused controller GEMMs (unchanged, validated).
// ---------------------------------------------------------------------------
__global__ __launch_bounds__(256) void k_gemm(
    const float* __restrict__ A,
    const float* __restrict__ Wk, const float* __restrict__ bk,
    const float* __restrict__ We, const float* __restrict__ be,
    const float* __restrict__ Ww, const float* __restrict__ bw,
    const float* __restrict__ Wg, const float* __restrict__ bg,
    float* __restrict__ ws, float* __restrict__ gout)
{
  __shared__ float As[32][68];
  __shared__ float Bs[32][68];

  const int bid = blockIdx.x;
  const int mat = bid >> 10;
  const int rem = bid & 1023;
  const int rt = rem >> 3, jt = rem & 7;
  const int rbase = rt * 64, jbase = jt * 64;

  const float* Wm; const float* bm;
  if      (mat == 0) { Wm = Wk; bm = bk; }
  else if (mat == 1) { Wm = We; bm = be; }
  else if (mat == 2) { Wm = Ww; bm = bw; }
  else               { Wm = Wg; bm = bg; }

  const int tid = threadIdx.x;
  const int lr = tid >> 2;
  const int lk = (tid & 3) * 8;
  const int ty = tid >> 4, tx = tid & 15;

  float acc[4][4] = {};

  for (int k0 = 0; k0 < Dc; k0 += 32) {
    const float4 a0 = *(const float4*)&A [(size_t)(rbase + lr) * Dc + k0 + lk];
    const float4 a1 = *(const float4*)&A [(size_t)(rbase + lr) * Dc + k0 + lk + 4];
    const float4 b0 = *(const float4*)&Wm[(size_t)(jbase + lr) * Dc + k0 + lk];
    const float4 b1 = *(const float4*)&Wm[(size_t)(jbase + lr) * Dc + k0 + lk + 4];
    __syncthreads();
    As[lk + 0][lr] = a0.x; As[lk + 1][lr] = a0.y; As[lk + 2][lr] = a0.z; As[lk + 3][lr] = a0.w;
    As[lk + 4][lr] = a1.x; As[lk + 5][lr] = a1.y; As[lk + 6][lr] = a1.z; As[lk + 7][lr] = a1.w;
    Bs[lk + 0][lr] = b0.x; Bs[lk + 1][lr] = b0.y; Bs[lk + 2][lr] = b0.z; Bs[lk + 3][lr] = b0.w;
    Bs[lk + 4][lr] = b1.x; Bs[lk + 5][lr] = b1.y; Bs[lk + 6][lr] = b1.z; Bs[lk + 7][lr] = b1.w;
    __syncthreads();
    #pragma unroll
    for (int kk = 0; kk < 32; ++kk) {
      const float4 av = *(const float4*)&As[kk][ty * 4];
      const float4 bv = *(const float4*)&Bs[kk][tx * 4];
      const float ar[4] = {av.x, av.y, av.z, av.w};
      const float br[4] = {bv.x, bv.y, bv.z, bv.w};
      #pragma unroll
      for (int i = 0; i < 4; ++i)
        #pragma unroll
        for (int j = 0; j < 4; ++j)
          acc[i][j] = fmaf(ar[i], br[j], acc[i][j]);
    }
  }

  const float4 bias = *(const float4*)&bm[jbase + tx * 4];
  const float bi[4] = {bias.x, bias.y, bias.z, bias.w};
  #pragma unroll
  for (int i = 0; i < 4; ++i) {
    const int r = rbase + ty * 4 + i;
    float v[4];
    #pragma unroll
    for (int j = 0; j < 4; ++j) {
      v[j] = acc[i][j] + bi[j];
      if (mat & 1) v[j] = sigm(v[j]);
    }
    float4 o; o.x = v[0]; o.y = v[1]; o.z = v[2]; o.w = v[3];
    if (mat == 3) {
      *(float4*)&gout[(size_t)r * Dc + jbase + tx * 4] = o;   // g -> d_out (temp)
    } else {
      float* dst = ws + (mat == 0 ? OFF_KN : (mat == 1 ? OFF_E : OFF_A));
      const int t = r & 255, b = r >> 8;                      // r = b*T + t
      *(float4*)&dst[((size_t)t * Bc + b) * Dc + jbase + tx * 4] = o;
    }
  }
}

// ---------------------------------------------------------------------------
// K2: l2-normalize k rows in place (unchanged).
// ---------------------------------------------------------------------------
__global__ __launch_bounds__(256) void k_knorm(float* __restrict__ kn)
{
  const int row = blockIdx.x * 4 + (threadIdx.x >> 6);
  const int lane = threadIdx.x & 63;
  float* p = kn + (size_t)row * Dc;
  float4 v0 = *(const float4*)&p[lane * 4];
  float4 v1 = *(const float4*)&p[256 + lane * 4];
  float ss = v0.x*v0.x + v0.y*v0.y + v0.z*v0.z + v0.w*v0.w
           + v1.x*v1.x + v1.y*v1.y + v1.z*v1.z + v1.w*v1.w;
  #pragma unroll
  for (int off = 32; off >= 1; off >>= 1) ss += __shfl_xor(ss, off);
  const float inv = 1.0f / fmaxf(sqrtf(ss), 1e-12f);
  v0.x *= inv; v0.y *= inv; v0.z *= inv; v0.w *= inv;
  v1.x *= inv; v1.y *= inv; v1.z *= inv; v1.w *= inv;
  *(float4*)&p[lane * 4] = v0;
  *(float4*)&p[256 + lane * 4] = v1;
}

// ---------------------------------------------------------------------------
// Flag-array device barrier. Arrivals are parallel stores to distinct lines;
// block 0 aggregates den partials (release-ordered before `go`). No RMWs.
// ---------------------------------------------------------------------------
DEV void gbar(unsigned* flags, unsigned* go, unsigned step, int bid, int tid,
              int do_agg, const float* denp_par, float* den_out, float* lds_red)
{
  __syncthreads();   // all waves done with phase work; vmcnt drained at barrier
  if (bid == 0) {
    if (tid > 0) {   // thread i polls block i's flag
      while (__hip_atomic_load(&flags[tid * 16], __ATOMIC_RELAXED,
                               __HIP_MEMORY_SCOPE_AGENT) < step)
        __builtin_amdgcn_s_sleep(2);
    }
    __syncthreads();
    if (do_agg) {    // den[idx][b] = sum over 128 W-block partials
      const int b = tid & 31, ch = tid >> 5;
      float s = 0.f;
      #pragma unroll
      for (int g = 0; g < 16; ++g)
        s += ld1cg(&denp_par[(size_t)(ch * 16 + g) * Bc + b]);
      lds_red[tid] = s;
      __syncthreads();
      if (tid < 32) {
        float tot = 0.f;
        #pragma unroll
        for (int c2 = 0; c2 < 8; ++c2) tot += lds_red[c2 * 32 + tid];
        st1cg(&den_out[tid], tot);
      }
    }
    __syncthreads();                 // drain den stores before release
    if (tid == 0)
      __hip_atomic_store(go, step, __ATOMIC_RELAXED, __HIP_MEMORY_SCOPE_AGENT);
  } else {
    if (tid == 0) {
      __hip_atomic_store(&flags[bid * 16], step, __ATOMIC_RELAXED,
                         __HIP_MEMORY_SCOPE_AGENT);
      while (__hip_atomic_load(go, __ATOMIC_RELAXED,
                               __HIP_MEMORY_SCOPE_AGENT) < step)
        __builtin_amdgcn_s_sleep(2);
    }
    __syncthreads();
  }
}

// ---------------------------------------------------------------------------
// sim phase: y = this block's 16 freshly written memory rows (LDS-resident).
// Writes ew (global, for R) + ew_own (LDS) + den partials (global).
// ---------------------------------------------------------------------------
DEV void sim_phase(const float* __restrict__ knp, float* __restrict__ ewn,
                   float* __restrict__ denp_row, const float (*y)[516],
                   float* __restrict__ ew_own,
                   const float* invn_s, float* sred, int s0, int tid)
{
  const int r = tid >> 4, bp = tid & 15;
  const float* k0p = knp + (size_t)bp * Dc;
  const float* k1p = knp + (size_t)(bp + 16) * Dc;
  float acc0 = 0.f, acc1 = 0.f;
  #pragma unroll 4
  for (int dq = 0; dq < Dc / 4; ++dq) {
    const float4 y4 = *(const float4*)&y[r][dq * 4];
    const float4 ka = *(const float4*)&k0p[dq * 4];
    const float4 kb = *(const float4*)&k1p[dq * 4];
    acc0 = fmaf(y4.x, ka.x, acc0); acc0 = fmaf(y4.y, ka.y, acc0);
    acc0 = fmaf(y4.z, ka.z, acc0); acc0 = fmaf(y4.w, ka.w, acc0);
    acc1 = fmaf(y4.x, kb.x, acc1); acc1 = fmaf(y4.y, kb.y, acc1);
    acc1 = fmaf(y4.z, kb.z, acc1); acc1 = fmaf(y4.w, kb.w, acc1);
  }
  const float iv = invn_s[r];
  const float e0 = __expf(acc0 * iv);
  const float e1 = __expf(acc1 * iv);
  st1cg(&ewn[(size_t)(s0 + r) * Bc + bp], e0);
  st1cg(&ewn[(size_t)(s0 + r) * Bc + bp + 16], e1);
  ew_own[r * 32 + bp]      = e0;
  ew_own[r * 32 + bp + 16] = e1;
  if (tid < 32) sred[tid] = 0.f;
  __syncthreads();
  atomicAdd(&sred[bp], e0);            // LDS atomics (block-local)
  atomicAdd(&sred[bp + 16], e1);
  __syncthreads();
  if (tid < 32) st1cg(&denp_row[tid], sred[tid]);
}

// ---------------------------------------------------------------------------
// Persistent recurrent kernel. 256 blocks (1/CU). W blocks keep their 16
// memory rows resident in LDS for all 256 steps.
// ---------------------------------------------------------------------------
__global__ __launch_bounds__(256) void k_main(
    const float* __restrict__ cs, const float* __restrict__ mem_in,
    const float* __restrict__ gamma, const float* __restrict__ beta,
    float* __restrict__ ws, float* __restrict__ out)
{
  __shared__ float mrows[16][516];   // persistent memory rows (W)
  __shared__ float xbuf[16][516];    // scratch: x staging (W) / ew tile (R)
  __shared__ float ew_own[16 * 32];  // own rows' exp(sim) at current t (W)
  __shared__ float wbuf[16][32];
  __shared__ float lds_red[256];
  __shared__ float sred[32];
  __shared__ float mu_s[16], rs_s[16], invn_s[16], dinv_s[32];

  float* kn   = ws + OFF_KN;
  float* eptb = ws + OFF_E;
  float* aptb = ws + OFF_A;
  float* memb = ws + OFF_MEM;
  float* ewb  = ws + OFF_EW;
  float* rp   = ws + OFF_RP;
  float* den  = ws + OFF_DEN;
  float* denp = ws + OFF_DENP;
  unsigned* flags = (unsigned*)(ws + OFF_FLAGS);
  unsigned* go    = (unsigned*)(ws + OFF_GO);

  const int bid = blockIdx.x, tid = threadIdx.x;
  const float inv32 = 1.0f / 32.0f;

  // ----- prologue: W loads its rows, publishes mem par0 / ew par0 / denp par0
  if (bid < NW) {
    const int s0 = bid * ROWS;
    const int c0 = tid * 2;
    #pragma unroll
    for (int r = 0; r < ROWS; ++r) {
      const float2 m = *(const float2*)&mem_in[(size_t)(s0 + r) * Dc + c0];
      *(float2*)&mrows[r][c0] = m;
      st2cg(&memb[(size_t)(s0 + r) * Dc + c0], m);
    }
    __syncthreads();
    {
      const int row = tid >> 4, li = tid & 15;
      float ss = 0.f;
      #pragma unroll
      for (int i = 0; i < 8; ++i) {
        const float4 v = *(const float4*)&mrows[row][(li + i * 16) * 4];
        ss += v.x*v.x + v.y*v.y + v.z*v.z + v.w*v.w;
      }
      ss += __shfl_xor(ss, 8); ss += __shfl_xor(ss, 4);
      ss += __shfl_xor(ss, 2); ss += __shfl_xor(ss, 1);
      if (li == 0) invn_s[row] = 1.0f / fmaxf(sqrtf(ss), 1e-12f);
    }
    __syncthreads();
    sim_phase(kn, ewb, denp + (size_t)bid * Bc, mrows, ew_own,
              invn_s, sred, s0, tid);
  }
  gbar(flags, go, 1u, bid, tid, 1, denp, den, lds_red);   // agg den[0]

  // ----- main loop -----
  for (int t = 0; t <= Tc; ++t) {
    if (bid < NW) {
      if (t < Tc - 1) {
        const int s0 = bid * ROWS;
        const int c0 = tid * 2;
        float* ewn  = ewb  + (size_t)((t + 1) & 1) * Sc * Bc;
        float* memn = memb + (size_t)((t + 1) & 1) * Sc * Dc;
        float* denp_n = denp + (size_t)((t + 1) & 1) * NW * Bc + (size_t)bid * Bc;

        if (tid < 32) dinv_s[tid] = 1.0f / ld1cg(&den[(size_t)t * Bc + tid]);
        __syncthreads();
        for (int idx = tid; idx < ROWS * 32; idx += 256)
          wbuf[idx >> 5][idx & 31] = ew_own[idx] * dinv_s[idx & 31];
        __syncthreads();

        // rank-32 erase/add update (e/a: normal cached loads, read-only)
        float2 er[ROWS] = {}, ad[ROWS] = {};
        const float* ept = eptb + (size_t)t * Bc * Dc;
        const float* apt = aptb + (size_t)t * Bc * Dc;
        #pragma unroll 4
        for (int b = 0; b < 32; ++b) {
          const float2 ev = *(const float2*)&ept[(size_t)b * Dc + c0];
          const float2 av = *(const float2*)&apt[(size_t)b * Dc + c0];
          #pragma unroll
          for (int r = 0; r < ROWS; ++r) {
            const float wv = wbuf[r][b];
            er[r].x = fmaf(wv, ev.x, er[r].x); er[r].y = fmaf(wv, ev.y, er[r].y);
            ad[r].x = fmaf(wv, av.x, ad[r].x); ad[r].y = fmaf(wv, av.y, ad[r].y);
          }
        }
        float2 xr[ROWS];
        #pragma unroll
        for (int r = 0; r < ROWS; ++r) {
          const float2 m = *(const float2*)&mrows[r][c0];
          float2 x;
          x.x = m.x * (1.0f - er[r].x * inv32) + ad[r].x * inv32;
          x.y = m.y * (1.0f - er[r].y * inv32) + ad[r].y * inv32;
          xr[r] = x;
          *(float2*)&xbuf[r][c0] = x;
        }
        __syncthreads();
        // LN stats per row
        {
          const int row = tid >> 4, li = tid & 15;
          float s1 = 0.f, s2 = 0.f;
          #pragma unroll
          for (int i = 0; i < 8; ++i) {
            const float4 v = *(const float4*)&xbuf[row][(li + i * 16) * 4];
            s1 += v.x + v.y + v.z + v.w;
            s2 += v.x*v.x + v.y*v.y + v.z*v.z + v.w*v.w;
          }
          s1 += __shfl_xor(s1, 8); s2 += __shfl_xor(s2, 8);
          s1 += __shfl_xor(s1, 4); s2 += __shfl_xor(s2, 4);
          s1 += __shfl_xor(s1, 2); s2 += __shfl_xor(s2, 2);
          s1 += __shfl_xor(s1, 1); s2 += __shfl_xor(s2, 1);
          if (li == 0) {
            const float mu = s1 * (1.0f / 512.0f);
            const float var = s2 * (1.0f / 512.0f) - mu * mu;
            mu_s[row] = mu;
            rs_s[row] = rsqrtf(var + 1e-5f);
          }
        }
        __syncthreads();
        const float2 gm  = *(const float2*)&gamma[c0];
        const float2 bt2 = *(const float2*)&beta[c0];
        #pragma unroll
        for (int r = 0; r < ROWS; ++r) {
          const float mu = mu_s[r], rs = rs_s[r];
          float2 y;
          y.x = (xr[r].x - mu) * rs * gm.x + bt2.x;
          y.y = (xr[r].y - mu) * rs * gm.y + bt2.y;
          *(float2*)&mrows[r][c0] = y;                        // update LDS state
          st2cg(&memn[(size_t)(s0 + r) * Dc + c0], y);        // publish for R
        }
        __syncthreads();
        // row l2 norms of new memory (from mrows)
        {
          const int row = tid >> 4, li = tid & 15;
          float ss = 0.f;
          #pragma unroll
          for (int i = 0; i < 8; ++i) {
            const float4 v = *(const float4*)&mrows[row][(li + i * 16) * 4];
            ss += v.x*v.x + v.y*v.y + v.z*v.z + v.w*v.w;
          }
          ss += __shfl_xor(ss, 8); ss += __shfl_xor(ss, 4);
          ss += __shfl_xor(ss, 2); ss += __shfl_xor(ss, 1);
          if (li == 0) invn_s[row] = 1.0f / fmaxf(sqrtf(ss), 1e-12f);
        }
        __syncthreads();
        sim_phase(kn + (size_t)(t + 1) * Bc * Dc, ewn, denp_n, mrows, ew_own,
                  invn_s, sred, s0, tid);
      }
    } else {
      const int rb = bid - NW;
      // O duty: gated output for step t-1
      if (rb < 8 && t >= 1) {
        const int t0 = t - 1;
        const float* rpc = rp + (size_t)(t0 & 1) * 16 * Bc * Dc;
        const int base = (rb * 256 + tid) * 8;
        const int b = base >> 9, d0 = base & 511;
        const float inv = 1.0f / ld1cg(&den[(size_t)t0 * Bc + b]);
        float r0[8] = {};
        #pragma unroll
        for (int si = 0; si < 16; ++si) {
          const float* q = rpc + ((size_t)si * Bc + b) * Dc + d0;
          const float2 p0 = ld2cg(q + 0);
          const float2 p1 = ld2cg(q + 2);
          const float2 p2 = ld2cg(q + 4);
          const float2 p3 = ld2cg(q + 6);
          r0[0] += p0.x; r0[1] += p0.y; r0[2] += p1.x; r0[3] += p1.y;
          r0[4] += p2.x; r0[5] += p2.y; r0[6] += p3.x; r0[7] += p3.y;
        }
        const size_t oofs = ((size_t)b * Tc + t0) * Dc + d0;
        const float4 g0 = *(const float4*)&out[oofs];
        const float4 g1 = *(const float4*)&out[oofs + 4];
        const float4 c0v = *(const float4*)&cs[oofs];
        const float4 c1v = *(const float4*)&cs[oofs + 4];
        float4 o0, o1;
        o0.x = g0.x * c0v.x + (1.0f - g0.x) * (r0[0] * inv);
        o0.y = g0.y * c0v.y + (1.0f - g0.y) * (r0[1] * inv);
        o0.z = g0.z * c0v.z + (1.0f - g0.z) * (r0[2] * inv);
        o0.w = g0.w * c0v.w + (1.0f - g0.w) * (r0[3] * inv);
        o1.x = g1.x * c1v.x + (1.0f - g1.x) * (r0[4] * inv);
        o1.y = g1.y * c1v.y + (1.0f - g1.y) * (r0[5] * inv);
        o1.z = g1.z * c1v.z + (1.0f - g1.z) * (r0[6] * inv);
        o1.w = g1.w * c1v.w + (1.0f - g1.w) * (r0[7] * inv);
        *(float4*)&out[oofs] = o0;
        *(float4*)&out[oofs + 4] = o1;
      }
      // R duty: unnormalized read partials for step t
      if (t < Tc) {
        const int si = rb >> 3, dj = rb & 7;
        const int sB = si * 128;
        const float* ewc = ewb + (size_t)(t & 1) * Sc * Bc;
        const float* memc = memb + (size_t)(t & 1) * Sc * Dc;
        float* ewl = (float*)xbuf;
        for (int i = tid; i < 128 * 32; i += 256)
          ewl[i] = ld1cg(&ewc[(size_t)sB * Bc + i]);
        __syncthreads();
        const int b = tid >> 3, dg = tid & 7;
        const int cbase = dj * 64 + dg * 8;
        float a0[8] = {};
        #pragma unroll 4
        for (int s = 0; s < 128; ++s) {
          const float wv = ewl[s * 32 + b];
          const float* mrow = memc + (size_t)(sB + s) * Dc + cbase;
          const float2 m0 = ld2cg(mrow + 0);
          const float2 m1 = ld2cg(mrow + 2);
          const float2 m2 = ld2cg(mrow + 4);
          const float2 m3 = ld2cg(mrow + 6);
          a0[0] = fmaf(wv, m0.x, a0[0]); a0[1] = fmaf(wv, m0.y, a0[1]);
          a0[2] = fmaf(wv, m1.x, a0[2]); a0[3] = fmaf(wv, m1.y, a0[3]);
          a0[4] = fmaf(wv, m2.x, a0[4]); a0[5] = fmaf(wv, m2.y, a0[5]);
          a0[6] = fmaf(wv, m3.x, a0[6]); a0[7] = fmaf(wv, m3.y, a0[7]);
        }
        float* dst = rp + (size_t)(t & 1) * 16 * Bc * Dc + ((size_t)si * Bc + b) * Dc + cbase;
        float2 w0; w0.x = a0[0]; w0.y = a0[1]; st2cg(dst + 0, w0);
        float2 w1; w1.x = a0[2]; w1.y = a0[3]; st2cg(dst + 2, w1);
        float2 w2; w2.x = a0[4]; w2.y = a0[5]; st2cg(dst + 4, w2);
        float2 w3; w3.x = a0[6]; w3.y = a0[7]; st2cg(dst + 6, w3);
      }
    }
    if (t < Tc) {
      const int do_agg = (t + 1 < Tc) ? 1 : 0;
      gbar(flags, go, (unsigned)(t + 2), bid, tid, do_agg,
           denp + (size_t)((t + 1) & 1) * NW * Bc,
           den + (size_t)(t + 1) * Bc, lds_red);
    }
  }
}

// ---------------------------------------------------------------------------
extern "C" void kernel_launch(void* const* d_in, const int* in_sizes, int n_in,
                              void* d_out, int out_size, void* d_ws, size_t ws_size,
                              hipStream_t stream)
{
  const float* cs    = (const float*)d_in[0];
  const float* mem   = (const float*)d_in[1];
  const float* Wk    = (const float*)d_in[2];
  const float* bk    = (const float*)d_in[3];
  const float* We    = (const float*)d_in[4];
  const float* be    = (const float*)d_in[5];
  const float* Ww    = (const float*)d_in[6];
  const float* bw    = (const float*)d_in[7];
  const float* Wg    = (const float*)d_in[8];
  const float* bg    = (const float*)d_in[9];
  const float* gamma = (const float*)d_in[10];
  const float* beta  = (const float*)d_in[11];
  float* ws  = (float*)d_ws;
  float* out = (float*)d_out;

  // zero barrier flags + go (captured as a graph node, replays each call)
  hipMemsetAsync(ws + OFF_FLAGS, 0, (256 * 16 + 1) * sizeof(unsigned), stream);

  hipLaunchKernelGGL(k_gemm, dim3(4096), dim3(256), 0, stream,
                     cs, Wk, bk, We, be, Ww, bw, Wg, bg, ws, out);
  hipLaunchKernelGGL(k_knorm, dim3(2048), dim3(256), 0, stream, ws + OFF_KN);
  hipLaunchKernelGGL(k_main, dim3(NBLK), dim3(256), 0, stream,
                     cs, mem, gamma, beta, ws, out);
}

// Round 5
// 10659.782 us; speedup vs baseline: 1.1395x; 1.1368x over previous
//
#include <hip/hip_runtime.h>

#define DEV __device__ __forceinline__

namespace {
constexpr int Bc = 32;
constexpr int Tc = 256;
constexpr int Dc = 512;
constexpr int NBLK = 256;
constexpr int NW   = 128;          // writer blocks (own 16 mem rows each)
constexpr int ROWS = 16;

// workspace layout (float offsets)
constexpr size_t OFF_KN   = 0;                                  // [T][B][D] normalized k
constexpr size_t OFF_E    = OFF_KN + (size_t)Tc * Bc * Dc;      // [T][B][D] sigmoid(erase)
constexpr size_t OFF_A    = OFF_E  + (size_t)Tc * Bc * Dc;      // [T][B][D] add
constexpr size_t OFF_RP   = OFF_A  + (size_t)Tc * Bc * Dc;      // [2][NW][B][D] read partials (normalized)
constexpr size_t OFF_DENP = OFF_RP + (size_t)2 * NW * Bc * Dc;  // [2][NW][B] den partials
constexpr size_t OFF_FLAGS= OFF_DENP + (size_t)2 * NW * Bc;     // 256*16 u32 arrival flags
constexpr size_t OFF_GO   = OFF_FLAGS + 256 * 16;               // 1 u32 release word
}

DEV float sigm(float x) { return 1.0f / (1.0f + __expf(-x)); }

// Agent-scope relaxed (sc1) helpers for cross-block state.
DEV float ld1cg(const float* p) {
  unsigned u = __hip_atomic_load((const unsigned*)p, __ATOMIC_RELAXED,
                                 __HIP_MEMORY_SCOPE_AGENT);
  return __uint_as_float(u);
}
DEV void st1cg(float* p, float v) {
  __hip_atomic_store((unsigned*)p, __float_as_uint(v), __ATOMIC_RELAXED,
                     __HIP_MEMORY_SCOPE_AGENT);
}
DEV float2 ld2cg(const float* p) {
  unsigned long long u = __hip_atomic_load((const unsigned long long*)p,
                                           __ATOMIC_RELAXED, __HIP_MEMORY_SCOPE_AGENT);
  union { unsigned long long u; float2 f; } c; c.u = u; return c.f;
}
DEV void st2cg(float* p, float2 v) {
  union { float2 f; unsigned long long u; } c; c.f = v;
  __hip_atomic_store((unsigned long long*)p, c.u, __ATOMIC_RELAXED,
                     __HIP_MEMORY_SCOPE_AGENT);
}

// ---------------------------------------------------------------------------
// K1: 4 fused controller GEMMs (unchanged, validated).
// ---------------------------------------------------------------------------
__global__ __launch_bounds__(256) void k_gemm(
    const float* __restrict__ A,
    const float* __restrict__ Wk, const float* __restrict__ bk,
    const float* __restrict__ We, const float* __restrict__ be,
    const float* __restrict__ Ww, const float* __restrict__ bw,
    const float* __restrict__ Wg, const float* __restrict__ bg,
    float* __restrict__ ws, float* __restrict__ gout)
{
  __shared__ float As[32][68];
  __shared__ float Bs[32][68];

  const int bid = blockIdx.x;
  const int mat = bid >> 10;
  const int rem = bid & 1023;
  const int rt = rem >> 3, jt = rem & 7;
  const int rbase = rt * 64, jbase = jt * 64;

  const float* Wm; const float* bm;
  if      (mat == 0) { Wm = Wk; bm = bk; }
  else if (mat == 1) { Wm = We; bm = be; }
  else if (mat == 2) { Wm = Ww; bm = bw; }
  else               { Wm = Wg; bm = bg; }

  const int tid = threadIdx.x;
  const int lr = tid >> 2;
  const int lk = (tid & 3) * 8;
  const int ty = tid >> 4, tx = tid & 15;

  float acc[4][4] = {};

  for (int k0 = 0; k0 < Dc; k0 += 32) {
    const float4 a0 = *(const float4*)&A [(size_t)(rbase + lr) * Dc + k0 + lk];
    const float4 a1 = *(const float4*)&A [(size_t)(rbase + lr) * Dc + k0 + lk + 4];
    const float4 b0 = *(const float4*)&Wm[(size_t)(jbase + lr) * Dc + k0 + lk];
    const float4 b1 = *(const float4*)&Wm[(size_t)(jbase + lr) * Dc + k0 + lk + 4];
    __syncthreads();
    As[lk + 0][lr] = a0.x; As[lk + 1][lr] = a0.y; As[lk + 2][lr] = a0.z; As[lk + 3][lr] = a0.w;
    As[lk + 4][lr] = a1.x; As[lk + 5][lr] = a1.y; As[lk + 6][lr] = a1.z; As[lk + 7][lr] = a1.w;
    Bs[lk + 0][lr] = b0.x; Bs[lk + 1][lr] = b0.y; Bs[lk + 2][lr] = b0.z; Bs[lk + 3][lr] = b0.w;
    Bs[lk + 4][lr] = b1.x; Bs[lk + 5][lr] = b1.y; Bs[lk + 6][lr] = b1.z; Bs[lk + 7][lr] = b1.w;
    __syncthreads();
    #pragma unroll
    for (int kk = 0; kk < 32; ++kk) {
      const float4 av = *(const float4*)&As[kk][ty * 4];
      const float4 bv = *(const float4*)&Bs[kk][tx * 4];
      const float ar[4] = {av.x, av.y, av.z, av.w};
      const float br[4] = {bv.x, bv.y, bv.z, bv.w};
      #pragma unroll
      for (int i = 0; i < 4; ++i)
        #pragma unroll
        for (int j = 0; j < 4; ++j)
          acc[i][j] = fmaf(ar[i], br[j], acc[i][j]);
    }
  }

  const float4 bias = *(const float4*)&bm[jbase + tx * 4];
  const float bi[4] = {bias.x, bias.y, bias.z, bias.w};
  #pragma unroll
  for (int i = 0; i < 4; ++i) {
    const int r = rbase + ty * 4 + i;
    float v[4];
    #pragma unroll
    for (int j = 0; j < 4; ++j) {
      v[j] = acc[i][j] + bi[j];
      if (mat & 1) v[j] = sigm(v[j]);
    }
    float4 o; o.x = v[0]; o.y = v[1]; o.z = v[2]; o.w = v[3];
    if (mat == 3) {
      *(float4*)&gout[(size_t)r * Dc + jbase + tx * 4] = o;   // g -> d_out (temp)
    } else {
      float* dst = ws + (mat == 0 ? OFF_KN : (mat == 1 ? OFF_E : OFF_A));
      const int t = r & 255, b = r >> 8;                      // r = b*T + t
      *(float4*)&dst[((size_t)t * Bc + b) * Dc + jbase + tx * 4] = o;
    }
  }
}

// ---------------------------------------------------------------------------
// K2: l2-normalize k rows in place (unchanged).
// ---------------------------------------------------------------------------
__global__ __launch_bounds__(256) void k_knorm(float* __restrict__ kn)
{
  const int row = blockIdx.x * 4 + (threadIdx.x >> 6);
  const int lane = threadIdx.x & 63;
  float* p = kn + (size_t)row * Dc;
  float4 v0 = *(const float4*)&p[lane * 4];
  float4 v1 = *(const float4*)&p[256 + lane * 4];
  float ss = v0.x*v0.x + v0.y*v0.y + v0.z*v0.z + v0.w*v0.w
           + v1.x*v1.x + v1.y*v1.y + v1.z*v1.z + v1.w*v1.w;
  #pragma unroll
  for (int off = 32; off >= 1; off >>= 1) ss += __shfl_xor(ss, off);
  const float inv = 1.0f / fmaxf(sqrtf(ss), 1e-12f);
  v0.x *= inv; v0.y *= inv; v0.z *= inv; v0.w *= inv;
  v1.x *= inv; v1.y *= inv; v1.z *= inv; v1.w *= inv;
  *(float4*)&p[lane * 4] = v0;
  *(float4*)&p[256 + lane * 4] = v1;
}

// ---------------------------------------------------------------------------
// Pure flag-array device barrier (no aggregation inside).
// ---------------------------------------------------------------------------
DEV void gbar(unsigned* flags, unsigned* go, unsigned step, int bid, int tid)
{
  __syncthreads();                 // drains vmcnt: all our stores are complete
  if (bid == 0) {
    if (tid > 0) {
      while (__hip_atomic_load(&flags[tid * 16], __ATOMIC_RELAXED,
                               __HIP_MEMORY_SCOPE_AGENT) < step)
        __builtin_amdgcn_s_sleep(2);
    }
    __syncthreads();
    if (tid == 0)
      __hip_atomic_store(go, step, __ATOMIC_RELAXED, __HIP_MEMORY_SCOPE_AGENT);
  } else {
    if (tid == 0) {
      __hip_atomic_store(&flags[bid * 16], step, __ATOMIC_RELAXED,
                         __HIP_MEMORY_SCOPE_AGENT);
      while (__hip_atomic_load(go, __ATOMIC_RELAXED,
                               __HIP_MEMORY_SCOPE_AGENT) < step)
        __builtin_amdgcn_s_sleep(2);
    }
    __syncthreads();
  }
}

// ---------------------------------------------------------------------------
// sim phase: y = this block's 16 memory rows (LDS). Produces ew_own (LDS only)
// and the block's den partial (sc1).
// ---------------------------------------------------------------------------
DEV void sim_phase(const float* __restrict__ knp, float* __restrict__ denp_row,
                   const float (*y)[516], float* __restrict__ ew_own,
                   const float* invn_s, float* sred, int tid)
{
  const int r = tid >> 4, bp = tid & 15;
  const float* k0p = knp + (size_t)bp * Dc;
  const float* k1p = knp + (size_t)(bp + 16) * Dc;
  float acc0 = 0.f, acc1 = 0.f;
  #pragma unroll 4
  for (int dq = 0; dq < Dc / 4; ++dq) {
    const float4 y4 = *(const float4*)&y[r][dq * 4];
    const float4 ka = *(const float4*)&k0p[dq * 4];
    const float4 kb = *(const float4*)&k1p[dq * 4];
    acc0 = fmaf(y4.x, ka.x, acc0); acc0 = fmaf(y4.y, ka.y, acc0);
    acc0 = fmaf(y4.z, ka.z, acc0); acc0 = fmaf(y4.w, ka.w, acc0);
    acc1 = fmaf(y4.x, kb.x, acc1); acc1 = fmaf(y4.y, kb.y, acc1);
    acc1 = fmaf(y4.z, kb.z, acc1); acc1 = fmaf(y4.w, kb.w, acc1);
  }
  const float iv = invn_s[r];
  const float e0 = __expf(acc0 * iv);
  const float e1 = __expf(acc1 * iv);
  ew_own[r * 32 + bp]      = e0;
  ew_own[r * 32 + bp + 16] = e1;
  if (tid < 32) sred[tid] = 0.f;
  __syncthreads();
  atomicAdd(&sred[bp], e0);            // LDS atomics (block-local)
  atomicAdd(&sred[bp + 16], e1);
  __syncthreads();
  if (tid < 32) st1cg(&denp_row[tid], sred[tid]);
}

// ---------------------------------------------------------------------------
// Persistent recurrent kernel, 256 blocks (1/CU).
//  blocks 0..127 (W): own 16 mem rows in LDS for the whole sequence.
//    step t: self-agg den_t -> w -> rp partial (normalized) -> erase/add+LN
//            -> sim(t+1) -> denp publish.
//  blocks 128..255 (Red): step t>=1: reduce rp(t-1) over the 128 partials and
//    write gated output for t-1 (reads g from `out` temp + cs).
// ---------------------------------------------------------------------------
__global__ __launch_bounds__(256) void k_main(
    const float* __restrict__ cs, const float* __restrict__ mem_in,
    const float* __restrict__ gamma, const float* __restrict__ beta,
    float* __restrict__ ws, float* __restrict__ out)
{
  __shared__ float mrows[16][516];   // persistent memory rows (W)
  __shared__ float ew_own[16 * 32];  // own rows' exp(sim) at current t (W)
  __shared__ float wbuf[16][32];
  __shared__ float lds_red[256];
  __shared__ float2 red2[256];
  __shared__ float sred[32];
  __shared__ float mu_s[16], rs_s[16], invn_s[16], dinv_s[32];

  float* kn   = ws + OFF_KN;
  float* eptb = ws + OFF_E;
  float* aptb = ws + OFF_A;
  float* rp   = ws + OFF_RP;
  float* denp = ws + OFF_DENP;
  unsigned* flags = (unsigned*)(ws + OFF_FLAGS);
  unsigned* go    = (unsigned*)(ws + OFF_GO);

  const int bid = blockIdx.x, tid = threadIdx.x;
  const float inv32 = 1.0f / 32.0f;

  // ----- prologue: W loads its rows, computes ew_0 / denp_0 -----
  if (bid < NW) {
    const int s0 = bid * ROWS;
    const int c0 = tid * 2;
    #pragma unroll
    for (int r = 0; r < ROWS; ++r)
      *(float2*)&mrows[r][c0] = *(const float2*)&mem_in[(size_t)(s0 + r) * Dc + c0];
    __syncthreads();
    {
      const int row = tid >> 4, li = tid & 15;
      float ss = 0.f;
      #pragma unroll
      for (int i = 0; i < 8; ++i) {
        const float4 v = *(const float4*)&mrows[row][(li + i * 16) * 4];
        ss += v.x*v.x + v.y*v.y + v.z*v.z + v.w*v.w;
      }
      ss += __shfl_xor(ss, 8); ss += __shfl_xor(ss, 4);
      ss += __shfl_xor(ss, 2); ss += __shfl_xor(ss, 1);
      if (li == 0) invn_s[row] = 1.0f / fmaxf(sqrtf(ss), 1e-12f);
    }
    __syncthreads();
    sim_phase(kn, denp + (size_t)bid * Bc, mrows, ew_own, invn_s, sred, tid);
  }
  gbar(flags, go, 1u, bid, tid);

  // ----- main loop: t = 0..256 -----
  for (int t = 0; t <= Tc; ++t) {
    if (bid < NW) {
      if (t < Tc) {
        const int c0 = tid * 2;
        // --- self-aggregate den_t from the 128 partials (parity t&1) ---
        {
          const float* dp = denp + (size_t)(t & 1) * NW * Bc;
          const int b = tid & 31, ch = tid >> 5;
          float s = 0.f;
          #pragma unroll
          for (int g = 0; g < 16; ++g)
            s += ld1cg(&dp[(size_t)(ch * 16 + g) * Bc + b]);
          lds_red[tid] = s;
          __syncthreads();
          if (tid < 32) {
            float tot = 0.f;
            #pragma unroll
            for (int c2 = 0; c2 < 8; ++c2) tot += lds_red[c2 * 32 + tid];
            dinv_s[tid] = 1.0f / tot;
          }
          __syncthreads();
        }
        // --- normalized weights for own rows ---
        for (int idx = tid; idx < ROWS * 32; idx += 256)
          wbuf[idx >> 5][idx & 31] = ew_own[idx] * dinv_s[idx & 31];
        __syncthreads();

        // --- preload own columns of the 16 rows ---
        float2 mr[ROWS];
        #pragma unroll
        for (int r = 0; r < ROWS; ++r) mr[r] = *(const float2*)&mrows[r][c0];

        // --- read partial: rp[bid][b][c0..c0+2) = sum_r w[r][b]*m[r][c] ---
        {
          float* rpd = rp + (size_t)(t & 1) * NW * Bc * Dc
                          + (size_t)bid * Bc * Dc + c0;
          #pragma unroll 4
          for (int b = 0; b < 32; ++b) {
            float2 a; a.x = 0.f; a.y = 0.f;
            #pragma unroll
            for (int r = 0; r < ROWS; ++r) {
              const float wv = wbuf[r][b];
              a.x = fmaf(wv, mr[r].x, a.x);
              a.y = fmaf(wv, mr[r].y, a.y);
            }
            st2cg(rpd + (size_t)b * Dc, a);
          }
        }

        if (t < Tc - 1) {
          // --- rank-32 erase/add update ---
          float2 er[ROWS] = {}, ad[ROWS] = {};
          const float* ept = eptb + (size_t)t * Bc * Dc;
          const float* apt = aptb + (size_t)t * Bc * Dc;
          #pragma unroll 4
          for (int b = 0; b < 32; ++b) {
            const float2 ev = *(const float2*)&ept[(size_t)b * Dc + c0];
            const float2 av = *(const float2*)&apt[(size_t)b * Dc + c0];
            #pragma unroll
            for (int r = 0; r < ROWS; ++r) {
              const float wv = wbuf[r][b];
              er[r].x = fmaf(wv, ev.x, er[r].x); er[r].y = fmaf(wv, ev.y, er[r].y);
              ad[r].x = fmaf(wv, av.x, ad[r].x); ad[r].y = fmaf(wv, av.y, ad[r].y);
            }
          }
          float2 xr[ROWS];
          #pragma unroll
          for (int r = 0; r < ROWS; ++r) {
            float2 x;
            x.x = mr[r].x * (1.0f - er[r].x * inv32) + ad[r].x * inv32;
            x.y = mr[r].y * (1.0f - er[r].y * inv32) + ad[r].y * inv32;
            xr[r] = x;
            *(float2*)&mrows[r][c0] = x;
          }
          __syncthreads();
          // LN stats per row (over staged x in mrows)
          {
            const int row = tid >> 4, li = tid & 15;
            float s1 = 0.f, s2 = 0.f;
            #pragma unroll
            for (int i = 0; i < 8; ++i) {
              const float4 v = *(const float4*)&mrows[row][(li + i * 16) * 4];
              s1 += v.x + v.y + v.z + v.w;
              s2 += v.x*v.x + v.y*v.y + v.z*v.z + v.w*v.w;
            }
            s1 += __shfl_xor(s1, 8); s2 += __shfl_xor(s2, 8);
            s1 += __shfl_xor(s1, 4); s2 += __shfl_xor(s2, 4);
            s1 += __shfl_xor(s1, 2); s2 += __shfl_xor(s2, 2);
            s1 += __shfl_xor(s1, 1); s2 += __shfl_xor(s2, 1);
            if (li == 0) {
              const float mu = s1 * (1.0f / 512.0f);
              const float var = s2 * (1.0f / 512.0f) - mu * mu;
              mu_s[row] = mu;
              rs_s[row] = rsqrtf(var + 1e-5f);
            }
          }
          __syncthreads();
          const float2 gm  = *(const float2*)&gamma[c0];
          const float2 bt2 = *(const float2*)&beta[c0];
          #pragma unroll
          for (int r = 0; r < ROWS; ++r) {
            const float mu = mu_s[r], rs = rs_s[r];
            float2 y;
            y.x = (xr[r].x - mu) * rs * gm.x + bt2.x;
            y.y = (xr[r].y - mu) * rs * gm.y + bt2.y;
            *(float2*)&mrows[r][c0] = y;
          }
          __syncthreads();
          // row l2 norms of new memory
          {
            const int row = tid >> 4, li = tid & 15;
            float ss = 0.f;
            #pragma unroll
            for (int i = 0; i < 8; ++i) {
              const float4 v = *(const float4*)&mrows[row][(li + i * 16) * 4];
              ss += v.x*v.x + v.y*v.y + v.z*v.z + v.w*v.w;
            }
            ss += __shfl_xor(ss, 8); ss += __shfl_xor(ss, 4);
            ss += __shfl_xor(ss, 2); ss += __shfl_xor(ss, 1);
            if (li == 0) invn_s[row] = 1.0f / fmaxf(sqrtf(ss), 1e-12f);
          }
          __syncthreads();
          sim_phase(kn + (size_t)(t + 1) * Bc * Dc,
                    denp + (size_t)((t + 1) & 1) * NW * Bc + (size_t)bid * Bc,
                    mrows, ew_own, invn_s, sred, tid);
        }
      }
    } else {
      // Reducer: out for step t-1
      if (t >= 1) {
        const int t0 = t - 1;
        const int rb = bid - NW;
        const int b = rb >> 2;
        const int d0 = (rb & 3) * 128;
        const float* rpc = rp + (size_t)(t0 & 1) * NW * Bc * Dc
                              + (size_t)b * Dc + d0;
        const int jp = (tid & 63) * 2;     // column pair within the 128-slice
        const int q  = tid >> 6;           // p-quarter
        float2 a; a.x = 0.f; a.y = 0.f;
        #pragma unroll 4
        for (int pi = 0; pi < 32; ++pi) {
          const int p = q * 32 + pi;
          const float2 v = ld2cg(rpc + (size_t)p * Bc * Dc + jp);
          a.x += v.x; a.y += v.y;
        }
        red2[tid] = a;
        __syncthreads();
        if (tid < 64) {
          const float2 v0 = red2[tid];
          const float2 v1 = red2[64 + tid];
          const float2 v2 = red2[128 + tid];
          const float2 v3 = red2[192 + tid];
          float2 rv;
          rv.x = (v0.x + v1.x) + (v2.x + v3.x);
          rv.y = (v0.y + v1.y) + (v2.y + v3.y);
          const size_t oofs = ((size_t)b * Tc + t0) * Dc + d0 + tid * 2;
          const float2 g  = *(const float2*)&out[oofs];
          const float2 cv = *(const float2*)&cs[oofs];
          float2 o;
          o.x = g.x * cv.x + (1.0f - g.x) * rv.x;
          o.y = g.y * cv.y + (1.0f - g.y) * rv.y;
          *(float2*)&out[oofs] = o;
        }
        __syncthreads();
      }
    }
    if (t < Tc) gbar(flags, go, (unsigned)(t + 2), bid, tid);
  }
}

// ---------------------------------------------------------------------------
extern "C" void kernel_launch(void* const* d_in, const int* in_sizes, int n_in,
                              void* d_out, int out_size, void* d_ws, size_t ws_size,
                              hipStream_t stream)
{
  const float* cs    = (const float*)d_in[0];
  const float* mem   = (const float*)d_in[1];
  const float* Wk    = (const float*)d_in[2];
  const float* bk    = (const float*)d_in[3];
  const float* We    = (const float*)d_in[4];
  const float* be    = (const float*)d_in[5];
  const float* Ww    = (const float*)d_in[6];
  const float* bw    = (const float*)d_in[7];
  const float* Wg    = (const float*)d_in[8];
  const float* bg    = (const float*)d_in[9];
  const float* gamma = (const float*)d_in[10];
  const float* beta  = (const float*)d_in[11];
  float* ws  = (float*)d_ws;
  float* out = (float*)d_out;

  // zero barrier flags + go
  hipMemsetAsync(ws + OFF_FLAGS, 0, (256 * 16 + 1) * sizeof(unsigned), stream);

  hipLaunchKernelGGL(k_gemm, dim3(4096), dim3(256), 0, stream,
                     cs, Wk, bk, We, be, Ww, bw, Wg, bg, ws, out);
  hipLaunchKernelGGL(k_knorm, dim3(2048), dim3(256), 0, stream, ws + OFF_KN);
  hipLaunchKernelGGL(k_main, dim3(NBLK), dim3(256), 0, stream,
                     cs, mem, gamma, beta, ws, out);
}

// Round 6
// 9902.103 us; speedup vs baseline: 1.2267x; 1.0765x over previous
//
#include <hip/hip_runtime.h>

#define DEV __device__ __forceinline__

namespace {
constexpr int Bc = 32;
constexpr int Tc = 256;
constexpr int Dc = 512;
constexpr int NBLK = 256;
constexpr int NW   = 128;          // writer blocks (own 16 mem rows each)
constexpr int ROWS = 16;

// workspace layout (float offsets)
constexpr size_t OFF_KN   = 0;                                  // [T][B][D] normalized k
constexpr size_t OFF_E    = OFF_KN + (size_t)Tc * Bc * Dc;      // [T][B][D] sigmoid(erase)
constexpr size_t OFF_A    = OFF_E  + (size_t)Tc * Bc * Dc;      // [T][B][D] add
constexpr size_t OFF_RP   = OFF_A  + (size_t)Tc * Bc * Dc;      // [2][NW][B][D] read partials
constexpr size_t OFF_DENP = OFF_RP + (size_t)2 * NW * Bc * Dc;  // [2][NW][B] den partials
constexpr size_t OFF_FLAGS= OFF_DENP + (size_t)2 * NW * Bc;     // 256*16 u32 arrival flags
}

DEV float sigm(float x) { return 1.0f / (1.0f + __expf(-x)); }

// Agent-scope relaxed (sc1) helpers for cross-block state.
DEV float ld1cg(const float* p) {
  unsigned u = __hip_atomic_load((const unsigned*)p, __ATOMIC_RELAXED,
                                 __HIP_MEMORY_SCOPE_AGENT);
  return __uint_as_float(u);
}
DEV void st1cg(float* p, float v) {
  __hip_atomic_store((unsigned*)p, __float_as_uint(v), __ATOMIC_RELAXED,
                     __HIP_MEMORY_SCOPE_AGENT);
}
DEV float2 ld2cg(const float* p) {
  unsigned long long u = __hip_atomic_load((const unsigned long long*)p,
                                           __ATOMIC_RELAXED, __HIP_MEMORY_SCOPE_AGENT);
  union { unsigned long long u; float2 f; } c; c.u = u; return c.f;
}
DEV void st2cg(float* p, float2 v) {
  union { float2 f; unsigned long long u; } c; c.f = v;
  __hip_atomic_store((unsigned long long*)p, c.u, __ATOMIC_RELAXED,
                     __HIP_MEMORY_SCOPE_AGENT);
}

// ---------------------------------------------------------------------------
// K1: 4 fused controller GEMMs (unchanged, validated).
// ---------------------------------------------------------------------------
__global__ __launch_bounds__(256) void k_gemm(
    const float* __restrict__ A,
    const float* __restrict__ Wk, const float* __restrict__ bk,
    const float* __restrict__ We, const float* __restrict__ be,
    const float* __restrict__ Ww, const float* __restrict__ bw,
    const float* __restrict__ Wg, const float* __restrict__ bg,
    float* __restrict__ ws, float* __restrict__ gout)
{
  __shared__ float As[32][68];
  __shared__ float Bs[32][68];

  const int bid = blockIdx.x;
  const int mat = bid >> 10;
  const int rem = bid & 1023;
  const int rt = rem >> 3, jt = rem & 7;
  const int rbase = rt * 64, jbase = jt * 64;

  const float* Wm; const float* bm;
  if      (mat == 0) { Wm = Wk; bm = bk; }
  else if (mat == 1) { Wm = We; bm = be; }
  else if (mat == 2) { Wm = Ww; bm = bw; }
  else               { Wm = Wg; bm = bg; }

  const int tid = threadIdx.x;
  const int lr = tid >> 2;
  const int lk = (tid & 3) * 8;
  const int ty = tid >> 4, tx = tid & 15;

  float acc[4][4] = {};

  for (int k0 = 0; k0 < Dc; k0 += 32) {
    const float4 a0 = *(const float4*)&A [(size_t)(rbase + lr) * Dc + k0 + lk];
    const float4 a1 = *(const float4*)&A [(size_t)(rbase + lr) * Dc + k0 + lk + 4];
    const float4 b0 = *(const float4*)&Wm[(size_t)(jbase + lr) * Dc + k0 + lk];
    const float4 b1 = *(const float4*)&Wm[(size_t)(jbase + lr) * Dc + k0 + lk + 4];
    __syncthreads();
    As[lk + 0][lr] = a0.x; As[lk + 1][lr] = a0.y; As[lk + 2][lr] = a0.z; As[lk + 3][lr] = a0.w;
    As[lk + 4][lr] = a1.x; As[lk + 5][lr] = a1.y; As[lk + 6][lr] = a1.z; As[lk + 7][lr] = a1.w;
    Bs[lk + 0][lr] = b0.x; Bs[lk + 1][lr] = b0.y; Bs[lk + 2][lr] = b0.z; Bs[lk + 3][lr] = b0.w;
    Bs[lk + 4][lr] = b1.x; Bs[lk + 5][lr] = b1.y; Bs[lk + 6][lr] = b1.z; Bs[lk + 7][lr] = b1.w;
    __syncthreads();
    #pragma unroll
    for (int kk = 0; kk < 32; ++kk) {
      const float4 av = *(const float4*)&As[kk][ty * 4];
      const float4 bv = *(const float4*)&Bs[kk][tx * 4];
      const float ar[4] = {av.x, av.y, av.z, av.w};
      const float br[4] = {bv.x, bv.y, bv.z, bv.w};
      #pragma unroll
      for (int i = 0; i < 4; ++i)
        #pragma unroll
        for (int j = 0; j < 4; ++j)
          acc[i][j] = fmaf(ar[i], br[j], acc[i][j]);
    }
  }

  const float4 bias = *(const float4*)&bm[jbase + tx * 4];
  const float bi[4] = {bias.x, bias.y, bias.z, bias.w};
  #pragma unroll
  for (int i = 0; i < 4; ++i) {
    const int r = rbase + ty * 4 + i;
    float v[4];
    #pragma unroll
    for (int j = 0; j < 4; ++j) {
      v[j] = acc[i][j] + bi[j];
      if (mat & 1) v[j] = sigm(v[j]);
    }
    float4 o; o.x = v[0]; o.y = v[1]; o.z = v[2]; o.w = v[3];
    if (mat == 3) {
      *(float4*)&gout[(size_t)r * Dc + jbase + tx * 4] = o;   // g -> d_out (temp)
    } else {
      float* dst = ws + (mat == 0 ? OFF_KN : (mat == 1 ? OFF_E : OFF_A));
      const int t = r & 255, b = r >> 8;                      // r = b*T + t
      *(float4*)&dst[((size_t)t * Bc + b) * Dc + jbase + tx * 4] = o;
    }
  }
}

// ---------------------------------------------------------------------------
// K2: l2-normalize k rows in place (unchanged).
// ---------------------------------------------------------------------------
__global__ __launch_bounds__(256) void k_knorm(float* __restrict__ kn)
{
  const int row = blockIdx.x * 4 + (threadIdx.x >> 6);
  const int lane = threadIdx.x & 63;
  float* p = kn + (size_t)row * Dc;
  float4 v0 = *(const float4*)&p[lane * 4];
  float4 v1 = *(const float4*)&p[256 + lane * 4];
  float ss = v0.x*v0.x + v0.y*v0.y + v0.z*v0.z + v0.w*v0.w
           + v1.x*v1.x + v1.y*v1.y + v1.z*v1.z + v1.w*v1.w;
  #pragma unroll
  for (int off = 32; off >= 1; off >>= 1) ss += __shfl_xor(ss, off);
  const float inv = 1.0f / fmaxf(sqrtf(ss), 1e-12f);
  v0.x *= inv; v0.y *= inv; v0.z *= inv; v0.w *= inv;
  v1.x *= inv; v1.y *= inv; v1.z *= inv; v1.w *= inv;
  *(float4*)&p[lane * 4] = v0;
  *(float4*)&p[256 + lane * 4] = v1;
}

// ---------------------------------------------------------------------------
// Single-hop all-to-all barrier: each block stores its flag; thread tid polls
// block tid's flag. One serial fabric hop per step.
// ---------------------------------------------------------------------------
DEV void gbar(unsigned* flags, unsigned step, int bid, int tid)
{
  __syncthreads();                 // all waves drain vmcnt -> stores coherent
  if (tid == 0)
    __hip_atomic_store(&flags[bid * 16], step, __ATOMIC_RELAXED,
                       __HIP_MEMORY_SCOPE_AGENT);
  while (__hip_atomic_load(&flags[tid * 16], __ATOMIC_RELAXED,
                           __HIP_MEMORY_SCOPE_AGENT) < step)
    __builtin_amdgcn_s_sleep(1);
  __syncthreads();
}

// ---------------------------------------------------------------------------
// sim phase: y = this block's 16 memory rows (LDS); kn from LDS staging.
// ---------------------------------------------------------------------------
DEV void sim_phase(const float (*knb)[516], float* __restrict__ denp_row,
                   const float (*y)[516], float* __restrict__ ew_own,
                   const float* invn_s, float* sred, int tid)
{
  const int r = tid >> 4, bp = tid & 15;
  float acc0 = 0.f, acc1 = 0.f;
  #pragma unroll 4
  for (int dq = 0; dq < Dc / 4; ++dq) {
    const float4 y4 = *(const float4*)&y[r][dq * 4];
    const float4 ka = *(const float4*)&knb[bp][dq * 4];
    const float4 kb = *(const float4*)&knb[bp + 16][dq * 4];
    acc0 = fmaf(y4.x, ka.x, acc0); acc0 = fmaf(y4.y, ka.y, acc0);
    acc0 = fmaf(y4.z, ka.z, acc0); acc0 = fmaf(y4.w, ka.w, acc0);
    acc1 = fmaf(y4.x, kb.x, acc1); acc1 = fmaf(y4.y, kb.y, acc1);
    acc1 = fmaf(y4.z, kb.z, acc1); acc1 = fmaf(y4.w, kb.w, acc1);
  }
  const float iv = invn_s[r];
  const float e0 = __expf(acc0 * iv);
  const float e1 = __expf(acc1 * iv);
  ew_own[r * 32 + bp]      = e0;
  ew_own[r * 32 + bp + 16] = e1;
  if (tid < 32) sred[tid] = 0.f;
  __syncthreads();
  atomicAdd(&sred[bp], e0);            // LDS atomics (block-local)
  atomicAdd(&sred[bp + 16], e1);
  __syncthreads();
  if (tid < 32) st1cg(&denp_row[tid], sred[tid]);
}

// ---------------------------------------------------------------------------
// Persistent recurrent kernel, 256 blocks (1 block/CU, 1 wave/SIMD).
// ---------------------------------------------------------------------------
__global__ __launch_bounds__(256, 1) void k_main(
    const float* __restrict__ cs, const float* __restrict__ mem_in,
    const float* __restrict__ gamma, const float* __restrict__ beta,
    float* __restrict__ ws, float* __restrict__ out)
{
  __shared__ float mrows[16][516];   // persistent memory rows (W)
  __shared__ float knbuf[32][516];   // staged kn[t+1] (W)
  __shared__ float ew_own[16 * 32];
  __shared__ float wbuf[16][32];
  __shared__ float lds_red[256];
  __shared__ float2 red2[256];
  __shared__ float sred[32];
  __shared__ float mu_s[16], rs_s[16], invn_s[16], dinv_s[32];

  float* kn   = ws + OFF_KN;
  float* eptb = ws + OFF_E;
  float* aptb = ws + OFF_A;
  float* rp   = ws + OFF_RP;
  float* denp = ws + OFF_DENP;
  unsigned* flags = (unsigned*)(ws + OFF_FLAGS);

  const int bid = blockIdx.x, tid = threadIdx.x;
  const float inv32 = 1.0f / 32.0f;

  // e/a cross-step register prefetch state (holds e[t]/a[t] during step t)
  float2 ev[32], av[32];

  if (bid < NW) {
    const int s0 = bid * ROWS;
    const int c0 = tid * 2;
    // load mem rows
    #pragma unroll
    for (int r = 0; r < ROWS; ++r)
      *(float2*)&mrows[r][c0] = *(const float2*)&mem_in[(size_t)(s0 + r) * Dc + c0];
    // stage kn[0]
    #pragma unroll
    for (int i = 0; i < 16; ++i) {
      const int idx = tid + i * 256;
      const int row = idx >> 7, col = (idx & 127) * 4;
      *(float4*)&knbuf[row][col] = *(const float4*)&kn[row * Dc + col];
    }
    // prefetch e[0]/a[0]
    #pragma unroll
    for (int b = 0; b < 32; ++b) {
      ev[b] = *(const float2*)&eptb[(size_t)b * Dc + c0];
      av[b] = *(const float2*)&aptb[(size_t)b * Dc + c0];
    }
    __syncthreads();
    {
      const int row = tid >> 4, li = tid & 15;
      float ss = 0.f;
      #pragma unroll
      for (int i = 0; i < 8; ++i) {
        const float4 v = *(const float4*)&mrows[row][(li + i * 16) * 4];
        ss += v.x*v.x + v.y*v.y + v.z*v.z + v.w*v.w;
      }
      ss += __shfl_xor(ss, 8); ss += __shfl_xor(ss, 4);
      ss += __shfl_xor(ss, 2); ss += __shfl_xor(ss, 1);
      if (li == 0) invn_s[row] = 1.0f / fmaxf(sqrtf(ss), 1e-12f);
    }
    __syncthreads();
    sim_phase(knbuf, denp + (size_t)bid * Bc, mrows, ew_own, invn_s, sred, tid);
  }
  gbar(flags, 1u, bid, tid);

  for (int t = 0; t <= Tc; ++t) {
    if (bid < NW) {
      if (t < Tc) {
        const int c0 = tid * 2;
        // 1) stage kn[t+1] (consumed by sim at end of this step)
        if (t < Tc - 1) {
          const float* src = kn + (size_t)(t + 1) * Bc * Dc;
          #pragma unroll
          for (int i = 0; i < 16; ++i) {
            const int idx = tid + i * 256;
            const int row = idx >> 7, col = (idx & 127) * 4;
            *(float4*)&knbuf[row][col] = *(const float4*)&src[row * Dc + col];
          }
        }
        // 2) den agg from 128 partials (parity t&1)
        {
          const float* dp = denp + (size_t)(t & 1) * NW * Bc;
          const int b = tid & 31, ch = tid >> 5;
          float s = 0.f;
          #pragma unroll
          for (int g = 0; g < 16; ++g)
            s += ld1cg(&dp[(size_t)(ch * 16 + g) * Bc + b]);
          lds_red[tid] = s;
          __syncthreads();
          if (tid < 32) {
            float tot = 0.f;
            #pragma unroll
            for (int c2 = 0; c2 < 8; ++c2) tot += lds_red[c2 * 32 + tid];
            dinv_s[tid] = 1.0f / tot;
          }
          __syncthreads();
        }
        // 3) normalized weights for own rows
        for (int idx = tid; idx < ROWS * 32; idx += 256)
          wbuf[idx >> 5][idx & 31] = ew_own[idx] * dinv_s[idx & 31];
        __syncthreads();

        // 4) read partial from current memory
        float2 mr[ROWS];
        #pragma unroll
        for (int r = 0; r < ROWS; ++r) mr[r] = *(const float2*)&mrows[r][c0];
        {
          float* rpd = rp + (size_t)(t & 1) * NW * Bc * Dc
                          + (size_t)bid * Bc * Dc + c0;
          #pragma unroll 4
          for (int b = 0; b < 32; ++b) {
            float2 a; a.x = 0.f; a.y = 0.f;
            #pragma unroll
            for (int r = 0; r < ROWS; ++r) {
              const float wv = wbuf[r][b];
              a.x = fmaf(wv, mr[r].x, a.x);
              a.y = fmaf(wv, mr[r].y, a.y);
            }
            st2cg(rpd + (size_t)b * Dc, a);
          }
        }

        if (t < Tc - 1) {
          // 5) erase/add from resident registers
          float2 er[ROWS] = {}, ad[ROWS] = {};
          #pragma unroll
          for (int b = 0; b < 32; ++b) {
            const float2 e2 = ev[b], a2 = av[b];
            #pragma unroll
            for (int r = 0; r < ROWS; ++r) {
              const float wv = wbuf[r][b];
              er[r].x = fmaf(wv, e2.x, er[r].x); er[r].y = fmaf(wv, e2.y, er[r].y);
              ad[r].x = fmaf(wv, a2.x, ad[r].x); ad[r].y = fmaf(wv, a2.y, ad[r].y);
            }
          }
          // 6) x staged into mrows
          float2 xr[ROWS];
          #pragma unroll
          for (int r = 0; r < ROWS; ++r) {
            float2 x;
            x.x = mr[r].x * (1.0f - er[r].x * inv32) + ad[r].x * inv32;
            x.y = mr[r].y * (1.0f - er[r].y * inv32) + ad[r].y * inv32;
            xr[r] = x;
            *(float2*)&mrows[r][c0] = x;
          }
          // 7) prefetch e[t+1]/a[t+1] (consumed next step)
          if (t <= Tc - 3) {
            const float* ep1 = eptb + (size_t)(t + 1) * Bc * Dc;
            const float* ap1 = aptb + (size_t)(t + 1) * Bc * Dc;
            #pragma unroll
            for (int b = 0; b < 32; ++b) {
              ev[b] = *(const float2*)&ep1[(size_t)b * Dc + c0];
              av[b] = *(const float2*)&ap1[(size_t)b * Dc + c0];
            }
          }
          __syncthreads();
          // 8) LN stats
          {
            const int row = tid >> 4, li = tid & 15;
            float s1 = 0.f, s2 = 0.f;
            #pragma unroll
            for (int i = 0; i < 8; ++i) {
              const float4 v = *(const float4*)&mrows[row][(li + i * 16) * 4];
              s1 += v.x + v.y + v.z + v.w;
              s2 += v.x*v.x + v.y*v.y + v.z*v.z + v.w*v.w;
            }
            s1 += __shfl_xor(s1, 8); s2 += __shfl_xor(s2, 8);
            s1 += __shfl_xor(s1, 4); s2 += __shfl_xor(s2, 4);
            s1 += __shfl_xor(s1, 2); s2 += __shfl_xor(s2, 2);
            s1 += __shfl_xor(s1, 1); s2 += __shfl_xor(s2, 1);
            if (li == 0) {
              const float mu = s1 * (1.0f / 512.0f);
              const float var = s2 * (1.0f / 512.0f) - mu * mu;
              mu_s[row] = mu;
              rs_s[row] = rsqrtf(var + 1e-5f);
            }
          }
          __syncthreads();
          const float2 gm  = *(const float2*)&gamma[c0];
          const float2 bt2 = *(const float2*)&beta[c0];
          #pragma unroll
          for (int r = 0; r < ROWS; ++r) {
            const float mu = mu_s[r], rs = rs_s[r];
            float2 y;
            y.x = (xr[r].x - mu) * rs * gm.x + bt2.x;
            y.y = (xr[r].y - mu) * rs * gm.y + bt2.y;
            *(float2*)&mrows[r][c0] = y;
          }
          __syncthreads();
          // 9) row l2 norms
          {
            const int row = tid >> 4, li = tid & 15;
            float ss = 0.f;
            #pragma unroll
            for (int i = 0; i < 8; ++i) {
              const float4 v = *(const float4*)&mrows[row][(li + i * 16) * 4];
              ss += v.x*v.x + v.y*v.y + v.z*v.z + v.w*v.w;
            }
            ss += __shfl_xor(ss, 8); ss += __shfl_xor(ss, 4);
            ss += __shfl_xor(ss, 2); ss += __shfl_xor(ss, 1);
            if (li == 0) invn_s[row] = 1.0f / fmaxf(sqrtf(ss), 1e-12f);
          }
          __syncthreads();
          // 10) sim for t+1 (kn from LDS staging)
          sim_phase(knbuf,
                    denp + (size_t)((t + 1) & 1) * NW * Bc + (size_t)bid * Bc,
                    mrows, ew_own, invn_s, sred, tid);
        }
      }
    } else {
      // Reducer: out for step t-1
      if (t >= 1) {
        const int t0 = t - 1;
        const int rb = bid - NW;
        const int b = rb >> 2;
        const int d0 = (rb & 3) * 128;
        const float* rpc = rp + (size_t)(t0 & 1) * NW * Bc * Dc
                              + (size_t)b * Dc + d0;
        const int jp = (tid & 63) * 2;
        const int q  = tid >> 6;
        float2 a; a.x = 0.f; a.y = 0.f;
        #pragma unroll 4
        for (int pi = 0; pi < 32; ++pi) {
          const int p = q * 32 + pi;
          const float2 v = ld2cg(rpc + (size_t)p * Bc * Dc + jp);
          a.x += v.x; a.y += v.y;
        }
        red2[tid] = a;
        __syncthreads();
        if (tid < 64) {
          const float2 v0 = red2[tid];
          const float2 v1 = red2[64 + tid];
          const float2 v2 = red2[128 + tid];
          const float2 v3 = red2[192 + tid];
          float2 rv;
          rv.x = (v0.x + v1.x) + (v2.x + v3.x);
          rv.y = (v0.y + v1.y) + (v2.y + v3.y);
          const size_t oofs = ((size_t)b * Tc + t0) * Dc + d0 + tid * 2;
          const float2 g  = *(const float2*)&out[oofs];
          const float2 cv = *(const float2*)&cs[oofs];
          float2 o;
          o.x = g.x * cv.x + (1.0f - g.x) * rv.x;
          o.y = g.y * cv.y + (1.0f - g.y) * rv.y;
          *(float2*)&out[oofs] = o;
        }
        __syncthreads();
      }
    }
    if (t < Tc) gbar(flags, (unsigned)(t + 2), bid, tid);
  }
}

// ---------------------------------------------------------------------------
extern "C" void kernel_launch(void* const* d_in, const int* in_sizes, int n_in,
                              void* d_out, int out_size, void* d_ws, size_t ws_size,
                              hipStream_t stream)
{
  const float* cs    = (const float*)d_in[0];
  const float* mem   = (const float*)d_in[1];
  const float* Wk    = (const float*)d_in[2];
  const float* bk    = (const float*)d_in[3];
  const float* We    = (const float*)d_in[4];
  const float* be    = (const float*)d_in[5];
  const float* Ww    = (const float*)d_in[6];
  const float* bw    = (const float*)d_in[7];
  const float* Wg    = (const float*)d_in[8];
  const float* bg    = (const float*)d_in[9];
  const float* gamma = (const float*)d_in[10];
  const float* beta  = (const float*)d_in[11];
  float* ws  = (float*)d_ws;
  float* out = (float*)d_out;

  // zero barrier flags
  hipMemsetAsync(ws + OFF_FLAGS, 0, 256 * 16 * sizeof(unsigned), stream);

  hipLaunchKernelGGL(k_gemm, dim3(4096), dim3(256), 0, stream,
                     cs, Wk, bk, We, be, Ww, bw, Wg, bg, ws, out);
  hipLaunchKernelGGL(k_knorm, dim3(2048), dim3(256), 0, stream, ws + OFF_KN);
  hipLaunchKernelGGL(k_main, dim3(NBLK), dim3(256), 0, stream,
                     cs, mem, gamma, beta, ws, out);
}